// Round 1
// 78.147 us; speedup vs baseline: 1.0184x; 1.0184x over previous
//
#include <hip/hip_runtime.h>

#define PI_F 3.14159265358979323846f
// SHARP * log2(e): sigmoid(SHARP*t) = 1/(1 + 2^(-SL*t))
constexpr float SL = 50.0f * 1.44269504089f;

__device__ __forceinline__ float fexp2(float x) {
#if __has_builtin(__builtin_amdgcn_exp2f)
  return __builtin_amdgcn_exp2f(x);
#else
  return __expf(x * 0.69314718056f);
#endif
}
__device__ __forceinline__ float frcp(float x) {
#if __has_builtin(__builtin_amdgcn_rcpf)
  return __builtin_amdgcn_rcpf(x);
#else
  return 1.0f / x;
#endif
}
__device__ __forceinline__ float fsig(float x) {
  return frcp(1.0f + fexp2(-x * 1.44269504089f));
}

// Fused kernel. Grid 65x65 (swizzled), block = 64 threads = 1 wave = one
// 16x16 padded-aligned pixel region. The 4 covering tiles are wave-uniform.
//
// Phase 1 (lanes 0..19): prep one stroke each (tile k=j/5, stroke j%5),
//   CULL strokes whose max alpha over this region is <= 2^-20 (center-point
//   bound in the stroke's rotated frame), then ballot-compact survivors into
//   an ordered LDS list:  A={X0,Y0,ct',st'} B={thrU,thrV,cR,cG} C={cB}.
//   X0 = 16c + 32*x0 (padded px units), ct' = cos*SL/32, thrU = SL*wd/2,
//   so SL*u = dxp*ct' + dyp*st' with dxp = (px+0.5) - X0.
// Phase 2: each thread owns 1 row x 4 cols (float4 per channel); loop over
//   the uniform stroke count UNROLLED BY 2 (independent exp/rcp chains);
//   u,w advance incrementally across the 4 columns.
// 1-wave block: __syncthreads replaced by s_waitcnt lgkmcnt(0) so the
// hoisted canvas loads are not drained at a barrier.
__global__ __launch_bounds__(64) void render_kernel(
    const float* __restrict__ param, const int* __restrict__ dec,
    const float* __restrict__ canvas, float* __restrict__ out) {
  __shared__ float4 ldsA[20];
  __shared__ float4 ldsB[20];
  __shared__ float  ldsC[20];

  // ---- Bijective XCD band swizzle (n=4225, q=528, r=1): each XCD gets a
  // contiguous band of regions -> horizontally adjacent regions share L2.
  const int bid = blockIdx.y * 65 + blockIdx.x;
  const int xcd = bid & 7;
  const int idx = bid >> 3;
  const int rid = (xcd == 0) ? idx : (529 + (xcd - 1) * 528 + idx);
  const int A = rid / 65;
  const int B = rid - A * 65;

  const int j = threadIdx.x;

  // ---- Hoisted canvas loads: overlap HBM latency with phase 1 ----
  const int cg = j & 3;        // column group (4 px)
  const int row = j >> 2;      // row within region (0..15)
  const int Xb = B * 16 - 8 + cg * 4;  // output col of float4 base
  const int Yr = A * 16 - 8 + row;     // output row
  const bool valid = ((unsigned)Xb < 1024u) & ((unsigned)Yr < 1024u);
  const size_t pix = (size_t)Yr * 1024 + Xb;
  float4 v0 = {}, v1 = {}, v2 = {};
  if (valid) {
    v0 = *(const float4*)(canvas + pix);
    v1 = *(const float4*)(canvas + pix + 1024 * 1024);
    v2 = *(const float4*)(canvas + pix + 2 * 1024 * 1024);
  }

  const int re = (A & 1) ? A - 1 : A;
  const int ro = (A & 1) ? A : A - 1;
  const int ce = (B & 1) ? B - 1 : B;
  const int co = (B & 1) ? B : B - 1;

  // ---- Phase 1: prep + cull (lanes 0..19) ----
  bool live = false;
  float4 w0q, w1q;
  float w2s = 0.0f;
  if (j < 20) {
    const int k = j / 5;           // tile slot in blend order
    const int i = j - k * 5;       // stroke index within tile
    // order: (re,ce), (ro,co), (ro,ce), (re,co)
    const int rr = (k == 0 || k == 3) ? re : ro;
    const int cc = (k & 1) ? co : ce;
    if ((unsigned)rr < 64u && (unsigned)cc < 64u) {
      const int sid = (rr * 64 + cc) * 5 + i;
      // issue dec and param loads together (no dec->param serialization)
      const int d = dec[sid];
      const float4* p4 = (const float4*)(param + (size_t)sid * 12);
      const float4 a = p4[0];  // params 0..3
      const float4 b = p4[1];  // params 4..7
      if (d != 0) {
        const float x0 = fsig(a.x), y0 = fsig(a.y);
        const float wd = fmaxf(fsig(a.z), 0.01f);
        const float ht = fmaxf(fsig(a.w), 0.01f);
        const float th = fsig(b.x) * PI_F;
        const float ct = __cosf(th), st = __sinf(th);
        const float ctp = ct * (SL / 32.0f), stp = st * (SL / 32.0f);
        const float X0 = (float)(cc * 16) + 32.0f * x0;
        const float Y0 = (float)(rr * 16) + 32.0f * y0;
        const float thU = SL * wd * 0.5f, thV = SL * ht * 0.5f;
        // ---- cull: bound log2(max alpha) over the 16x16 region ----
        // region pixel centers span center +- 7.5 px in each axis.
        const float dxc = ((float)(B * 16) + 8.0f) - X0;
        const float dyc = ((float)(A * 16) + 8.0f) - Y0;
        const float uc = dxc * ctp + dyc * stp;   // SL*u at region center
        const float vc = dyc * ctp - dxc * stp;   // SL*v at region center
        const float dd = (fabsf(ctp) + fabsf(stp)) * 7.5f;
        const float tu = fminf(thU - fabsf(uc) + dd, 0.0f);
        const float tv = fminf(thV - fabsf(vc) + dd, 0.0f);
        // alpha <= 2^(tu+tv); skip if below 2^-20 (err <= 20*2^-20 ~ 2e-5)
        if (tu + tv >= -20.0f) {
          w0q = make_float4(X0, Y0, ctp, stp);
          w1q = make_float4(thU, thV, fsig(b.y), fsig(b.z));
          w2s = fsig(b.w);
          live = true;
        }
      }
    }
  }
  const unsigned long long mask = __ballot(live);
  const int total = __popcll(mask);  // wave-uniform surviving-stroke count
  if (live) {
    const int off = __popcll(mask & ((1ull << j) - 1));
    ldsA[off] = w0q;
    ldsB[off] = w1q;
    ldsC[off] = w2s;
  }
  // 1-wave workgroup: LDS ops complete in order per wave; only need the
  // counter drained before cross-lane reads. Avoids vmcnt(0) barrier drain.
  asm volatile("s_waitcnt lgkmcnt(0)" ::: "memory");
  if (!valid) return;

  // ---- Phase 2: composite ----
  const float fx0 = (float)(B * 16 + cg * 4) + 0.5f;  // padded px coords
  const float fy  = (float)(A * 16 + row) + 0.5f;

  float* pv0 = &v0.x;
  float* pv1 = &v1.x;
  float* pv2 = &v2.x;

  int s = 0;
  for (; s + 2 <= total; s += 2) {  // unroll-2: two independent trans chains
    const float4 qa0 = ldsA[s],     qb0 = ldsB[s];
    const float4 qa1 = ldsA[s + 1], qb1 = ldsB[s + 1];
    const float  qc0 = ldsC[s],     qc1 = ldsC[s + 1];
    float al0[4], al1[4];
    {
      const float dx0 = fx0 - qa0.x, dy = fy - qa0.y;
      float u = dx0 * qa0.z + dy * qa0.w;
      float w = dy * qa0.z - dx0 * qa0.w;
#pragma unroll
      for (int m = 0; m < 4; ++m) {
        const float e1 = fexp2(fabsf(u) - qb0.x);
        const float e2 = fexp2(fabsf(w) - qb0.y);
        al0[m] = frcp((1.0f + e1) * (1.0f + e2));
        u += qa0.z;  w -= qa0.w;
      }
    }
    {
      const float dx0 = fx0 - qa1.x, dy = fy - qa1.y;
      float u = dx0 * qa1.z + dy * qa1.w;
      float w = dy * qa1.z - dx0 * qa1.w;
#pragma unroll
      for (int m = 0; m < 4; ++m) {
        const float e1 = fexp2(fabsf(u) - qb1.x);
        const float e2 = fexp2(fabsf(w) - qb1.y);
        al1[m] = frcp((1.0f + e1) * (1.0f + e2));
        u += qa1.z;  w -= qa1.w;
      }
    }
    // apply blends in stroke order (alphas independent of canvas -> exact)
#pragma unroll
    for (int m = 0; m < 4; ++m) {
      pv0[m] = fmaf(al0[m], qb0.z - pv0[m], pv0[m]);
      pv1[m] = fmaf(al0[m], qb0.w - pv1[m], pv1[m]);
      pv2[m] = fmaf(al0[m], qc0   - pv2[m], pv2[m]);
      pv0[m] = fmaf(al1[m], qb1.z - pv0[m], pv0[m]);
      pv1[m] = fmaf(al1[m], qb1.w - pv1[m], pv1[m]);
      pv2[m] = fmaf(al1[m], qc1   - pv2[m], pv2[m]);
    }
  }
  if (s < total) {  // tail stroke
    const float4 qa = ldsA[s], qb = ldsB[s];
    const float  qc = ldsC[s];
    const float dx0 = fx0 - qa.x, dy = fy - qa.y;
    float u = dx0 * qa.z + dy * qa.w;
    float w = dy * qa.z - dx0 * qa.w;
#pragma unroll
    for (int m = 0; m < 4; ++m) {
      const float e1 = fexp2(fabsf(u) - qb.x);
      const float e2 = fexp2(fabsf(w) - qb.y);
      const float al = frcp((1.0f + e1) * (1.0f + e2));
      pv0[m] = fmaf(al, qb.z - pv0[m], pv0[m]);
      pv1[m] = fmaf(al, qb.w - pv1[m], pv1[m]);
      pv2[m] = fmaf(al, qc   - pv2[m], pv2[m]);
      u += qa.z;  w -= qa.w;
    }
  }

  *(float4*)(out + pix) = v0;
  *(float4*)(out + pix + 1024 * 1024) = v1;
  *(float4*)(out + pix + 2 * 1024 * 1024) = v2;
}

extern "C" void kernel_launch(void* const* d_in, const int* in_sizes, int n_in,
                              void* d_out, int out_size, void* d_ws, size_t ws_size,
                              hipStream_t stream) {
  const float* param  = (const float*)d_in[0];
  const int*   dec    = (const int*)d_in[1];
  const float* canvas = (const float*)d_in[2];
  float* outp = (float*)d_out;
  (void)d_ws; (void)ws_size;

  dim3 grid(65, 65, 1);
  render_kernel<<<grid, 64, 0, stream>>>(param, dec, canvas, outp);
}